// Round 4
// baseline (69.470 us; speedup 1.0000x reference)
//
#include <hip/hip_runtime.h>
#include <math.h>

// out[p] = prod_l (1 - V[l,p]) * poly(wl[p])
//   V = A_l/(gamma^2+d^2) + A_g*exp(n2*d^2),  d = wl - lam
//
// Fully fused single kernel, 4-wave line-split, barrier-light version:
//  - block = 256 threads = 4 waves over the SAME 64 pixels; wave w owns
//    lines i ≡ w (mod 4) of the band. 6252 waves = 24.4 waves/CU -> whole
//    grid resident in ONE scheduling round; kernel wall ~= per-block
//    latency chain, so this version attacks serialization points:
//  - search keys computed ANALYTICALLY from wl's linspace structure
//    (spec-fixed). Only the +/-10 A band EDGE depends on the formula --
//    evaluation still reads wl from memory -- and the Lorentzian tail at
//    the edge (~7e-4) is 30x under the 2e-2 threshold, so sub-ppm formula
//    error is irrelevant. This decouples the search from the wl load.
//  - 2-round sampled wave-parallel search (64 probes, ballot+popc bracket,
//    round 2 resolves; both bounds share the round-1 probe) executed
//    REDUNDANTLY by every wave: no bnd LDS, no barrier.
//  - each wave stages its OWN lines into a PRIVATE LDS slice (lane j ->
//    line base+wv+4j). Within-wave LDS ops are in-order (per-wave DS
//    pipeline -- same guarantee ds_bpermute relies on), so no barrier;
//    wave_barrier() only pins compile-time order.
//  - block-wide barriers: 3 -> 1 (final cross-wave product combine).
//  - Gaussian gated on |d| < 3.5 A (8*sigma_max: exp(-32) ~ 1e-14); 64-px
//    span is 1.3 A so the gate is nearly wave-uniform.
//  - Lorentzian tail-sum beyond D_LOR=10: ~0.0072/D -> 7e-4, 30x under
//    threshold (unchanged from verified baseline).

#define PX       64
#define NW       4
#define NTHREADS (PX * NW)
#define D_LOR    10.0f
#define D_GAU    3.5f
#define WL_LO_C  9000.0f
#define WL_HI_C  11000.0f

__global__ void __launch_bounds__(NTHREADS) fused_voigt_kernel(
        const float* __restrict__ wl,
        const float* __restrict__ lam,
        const float* __restrict__ amp_log,
        const float* __restrict__ sig_log,
        const float* __restrict__ gam_log,
        const float* __restrict__ a_c,
        const float* __restrict__ b_c,
        const float* __restrict__ c_c,
        float* __restrict__ out,
        int n_pix, int n_lines) {
    __shared__ float4 q_s[NW][64];      // per-wave slice: lam, Al, g^2, n2
    __shared__ float  ag_s[NW][64];     // per-wave slice: Ag
    __shared__ float  part[NW - 1][PX]; // waves 1..3 partial products

    const int tid  = threadIdx.x;
    const int wv   = tid >> 6;
    const int lane = tid & 63;
    const int p0   = blockIdx.x * PX;
    const int p    = p0 + lane;
    const int pc   = min(p, n_pix - 1);

    const float w  = wl[pc];      // issued early; search does NOT wait on it
    const float ac = a_c[0];
    const float bc = b_c[0];
    const float cc = c_c[0];

    // analytic band keys (search only; evaluation uses loaded w)
    const float wstep = (WL_HI_C - WL_LO_C) / (float)(n_pix - 1);
    const float vlo = WL_LO_C + (float)p0 * wstep - D_LOR;
    const float vhi = WL_LO_C + (float)(p0 + PX - 1) * wstep + D_LOR;

    // 2-round sampled search, both bounds at once, every wave redundantly.
    const int step = (n_lines + 63) >> 6;          // ceil(n/64)
    const int si   = lane * step;
    const bool sv  = si < n_lines;
    const float sx = lam[sv ? si : (n_lines - 1)];
    const int jlo = __popcll(__ballot(sv && (sx < vlo)));
    const int jhi = __popcll(__ballot(sv && (sx < vhi)));
    const int blo = (jlo == 0) ? 0 : (jlo - 1) * step + 1;
    const int bhi = (jhi == 0) ? 0 : (jhi - 1) * step + 1;
    // round 2: over-probing past the bracket is safe (sorted => those
    // probes are >= key, ballot bits 0), same as the verified R3 search.
    const int il = blo + lane, ih = bhi + lane;
    const bool v2l = il < n_lines, v2h = ih < n_lines;
    const float xl = lam[v2l ? il : (n_lines - 1)];
    const float xh = lam[v2h ? ih : (n_lines - 1)];
    const int lo = blo + __popcll(__ballot(v2l && (xl < vlo)));
    const int hi = bhi + __popcll(__ballot(v2h && (xh < vhi)));

    float prod0 = 1.0f, prod1 = 1.0f;

    for (int base = lo; base < hi; base += NW * 64) {
        const int l = base + wv + NW * lane;   // lane j stages wave's line j
        if (l < hi) {
            float sigma = __expf(sig_log[l]);
            float gamma = __expf(gam_log[l]);
            float amp   = __expf(amp_log[l]);
            float fG = 2.3548f * sigma;
            float fL = 2.0f * gamma;
            float fG2 = fG * fG, fL2 = fL * fL;
            float fwhm5 = fG2 * fG2 * fG
                        + 2.69269f * fG2 * fG2 * fL
                        + 2.42843f * fG2 * fG  * fL2
                        + 4.47163f * fG2 * fL2 * fL
                        + 0.07842f * fG  * fL2 * fL2
                        + fL2 * fL2 * fL;
            float fwhm = __expf(0.2f * __logf(fwhm5));   // fwhm5^(1/5)
            float fr   = fL * __builtin_amdgcn_rcpf(fwhm);
            float eta  = fr * (1.36603f + fr * (-0.47719f + fr * 0.11116f));
            float Al   = amp * eta * gamma * (1.0f / 3.141592654f);
            float Ag   = amp * (1.0f - eta) *
                         __builtin_amdgcn_rcpf(sigma * 2.5066f);
            q_s[wv][lane]  = make_float4(lam[l], Al, gamma * gamma,
                                         -0.5f / (sigma * sigma));
            ag_s[wv][lane] = Ag;
        }
        __builtin_amdgcn_wave_barrier();  // compile-order pin only; per-wave
                                          // DS pipeline is in-order in HW

        const int rem = hi - base - wv;
        const int nlw = (rem > 0) ? min(64, (rem + 3) >> 2) : 0;

        int i = 0;
        for (; i + 1 < nlw; i += 2) {
            float4 qa = q_s[wv][i];
            float4 qb = q_s[wv][i + 1];
            float aga = ag_s[wv][i];
            float agb = ag_s[wv][i + 1];
            float da = w - qa.x, db = w - qb.x;
            float da2 = da * da, db2 = db * db;
            float va = qa.y * __builtin_amdgcn_rcpf(qa.z + da2);
            float vb = qb.y * __builtin_amdgcn_rcpf(qb.z + db2);
            if (fabsf(da) < D_GAU) va += aga * __expf(qa.w * da2);
            if (fabsf(db) < D_GAU) vb += agb * __expf(qb.w * db2);
            prod0 *= (1.0f - va);
            prod1 *= (1.0f - vb);
        }
        for (; i < nlw; ++i) {
            float4 q = q_s[wv][i];
            float d  = w - q.x;
            float d2 = d * d;
            float v  = q.y * __builtin_amdgcn_rcpf(q.z + d2);
            if (fabsf(d) < D_GAU) v += ag_s[wv][i] * __expf(q.w * d2);
            prod0 *= (1.0f - v);
        }
    }

    if (wv) part[wv - 1][lane] = prod0 * prod1;
    __syncthreads();                    // the ONLY block-wide barrier

    if (wv == 0 && p < n_pix) {
        float wn = (w - 10500.0f) * (1.0f / 2500.0f);
        float poly = ac + wn * (bc + wn * cc);
        out[p] = (prod0 * prod1) * part[0][lane] * part[1][lane] *
                 part[2][lane] * poly;
    }
}

extern "C" void kernel_launch(void* const* d_in, const int* in_sizes, int n_in,
                              void* d_out, int out_size, void* d_ws, size_t ws_size,
                              hipStream_t stream) {
    const float* wl      = (const float*)d_in[0];
    const float* lam     = (const float*)d_in[1];
    const float* amp_log = (const float*)d_in[2];
    const float* sig_log = (const float*)d_in[3];
    const float* gam_log = (const float*)d_in[4];
    const float* a_c     = (const float*)d_in[5];
    const float* b_c     = (const float*)d_in[6];
    const float* c_c     = (const float*)d_in[7];
    float* out = (float*)d_out;

    int n_pix   = in_sizes[0];
    int n_lines = in_sizes[1];
    int n_blocks = (n_pix + PX - 1) / PX;

    fused_voigt_kernel<<<n_blocks, NTHREADS, 0, stream>>>(
        wl, lam, amp_log, sig_log, gam_log, a_c, b_c, c_c, out,
        n_pix, n_lines);
}